// Round 8
// baseline (187.828 us; speedup 1.0000x reference)
//
#include <hip/hip_runtime.h>
#include <hip/hip_bf16.h>
#include <math.h>

// B=4, C=256, N=4096, QP=32.
// ws: qH[b][n][32] f16 (PRE-SCALED by log2e), kH[b][n][32] f16,
//     vHT[b][c][n] f16, wH[320][256] f16 (Wq rows scaled), ms4[4][b][n] f32.
// K3 attn (R8): software-pipelined P (PV lags one tile, P in regs),
//   v triple-buffered via global_load_lds (1 barrier/tile), -mfix folded
//   into the S accumulator init.

#define NBATCH 4
#define CDIM   256
#define NSEQ   4096
#define QPDIM  32
#define LOG2E  1.44269504088896340736f

typedef _Float16 half8_t  __attribute__((ext_vector_type(8)));
typedef _Float16 half2_t  __attribute__((ext_vector_type(2)));
typedef float    floatx4  __attribute__((ext_vector_type(4)));
typedef float    floatx16 __attribute__((ext_vector_type(16)));

union H8 { half8_t h8; half2_t h2[4]; int i32[4]; };

__device__ inline half2_t pack_f16(float a, float b) {
    return __builtin_bit_cast(half2_t, __builtin_amdgcn_cvt_pkrtz(a, b));
}

// ---------------------------------------------------------------------------
// K0: W -> f16, Wq rows scaled by log2e. 40 blocks x 256 thr x 8 elems.
// ---------------------------------------------------------------------------
__global__ __launch_bounds__(256) void wprep_kernel(
    const float* __restrict__ Wv, const float* __restrict__ Wq,
    const float* __restrict__ Wk, _Float16* __restrict__ wH)
{
    const int idx = blockIdx.x * 256 + threadIdx.x;
    const int e = idx * 8;
    const int r = e >> 8, c = e & 255;
    const float* src;
    float scale = 1.0f;
    if (r < 256)      src = Wv + (size_t)r * 256 + c;
    else if (r < 288) { src = Wq + (size_t)(r - 256) * 256 + c; scale = LOG2E; }
    else              src = Wk + (size_t)(r - 288) * 256 + c;
    float4 f0 = ((const float4*)src)[0];
    float4 f1 = ((const float4*)src)[1];
    half8_t h;
    h[0] = (_Float16)(f0.x * scale); h[1] = (_Float16)(f0.y * scale);
    h[2] = (_Float16)(f0.z * scale); h[3] = (_Float16)(f0.w * scale);
    h[4] = (_Float16)(f1.x * scale); h[5] = (_Float16)(f1.y * scale);
    h[6] = (_Float16)(f1.z * scale); h[7] = (_Float16)(f1.w * scale);
    *(half8_t*)(wH + (size_t)r * 256 + c) = h;
}

// ---------------------------------------------------------------------------
// K1: qkv GEMM. grid = 4b x 128 nt(32 n) = 512 blocks, 256 thr (4 waves).
// Coalesced staging: 8 lanes sweep one 128B row. Wave w: 80 rows x 32 n.
// ---------------------------------------------------------------------------
__global__ __launch_bounds__(256, 4) void qkv_kernel(
    const float* __restrict__ x, const _Float16* __restrict__ wH,
    const float* __restrict__ bq, const float* __restrict__ bk,
    const float* __restrict__ bv,
    _Float16* __restrict__ qH, _Float16* __restrict__ kH,
    _Float16* __restrict__ vHT)
{
    __shared__ _Float16 xT[32][264];   // [n][c]

    const int blk  = blockIdx.x;
    const int slot = blk & 7;
    const int b    = slot >> 1;
    const int n0   = (((blk >> 3) << 1) | (slot & 1)) << 5;  // 32-n tile
    const int t    = threadIdx.x;
    const int w    = t >> 6;
    const int lane = t & 63;
    const int quad = lane >> 4;
    const int col  = lane & 15;

    // ---- stage x[b, :, n0..n0+31] transposed -> f16 (coalesced rows) ----
    {
        const int crow = t >> 3;           // 0..31
        const int np   = t & 7;            // 8 lanes x 16B = one 128B row
        #pragma unroll
        for (int pass = 0; pass < 8; ++pass) {
            const int c = pass * 32 + crow;
            float4 f = *(const float4*)(
                x + ((size_t)(b * CDIM + c)) * NSEQ + n0 + np * 4);
            xT[np * 4 + 0][c] = (_Float16)f.x;
            xT[np * 4 + 1][c] = (_Float16)f.y;
            xT[np * 4 + 2][c] = (_Float16)f.z;
            xT[np * 4 + 3][c] = (_Float16)f.w;
        }
    }
    __syncthreads();

    // ---- GEMM: wave w -> rows w*80 .. +79 (5 m-tiles of 16), 32 n ----
    const int r0 = w * 80;
    floatx4 acc[5][2];
    #pragma unroll
    for (int mt = 0; mt < 5; ++mt) {
        acc[mt][0] = (floatx4){0.f, 0.f, 0.f, 0.f};
        acc[mt][1] = (floatx4){0.f, 0.f, 0.f, 0.f};
    }
    #pragma unroll
    for (int ks = 0; ks < 8; ++ks) {
        half8_t bf0 = *(const half8_t*)&xT[col][ks * 32 + quad * 8];
        half8_t bf1 = *(const half8_t*)&xT[16 + col][ks * 32 + quad * 8];
        #pragma unroll
        for (int mt = 0; mt < 5; ++mt) {
            half8_t a = *(const half8_t*)(
                wH + (size_t)(r0 + mt * 16 + col) * 256 + ks * 32 + quad * 8);
            acc[mt][0] = __builtin_amdgcn_mfma_f32_16x16x32_f16(
                a, bf0, acc[mt][0], 0, 0, 0);
            acc[mt][1] = __builtin_amdgcn_mfma_f32_16x16x32_f16(
                a, bf1, acc[mt][1], 0, 0, 0);
        }
    }

    // ---- epilogue ----
    #pragma unroll
    for (int mt = 0; mt < 5; ++mt) {
        const int gbase = r0 + mt * 16;
        const float* bp; int rl; float bscale = 1.0f;
        if (gbase < 256)      { bp = bv; rl = gbase; }
        else if (gbase < 288) { bp = bq; rl = gbase - 256; bscale = LOG2E; }
        else                  { bp = bk; rl = gbase - 288; }
        #pragma unroll
        for (int reg = 0; reg < 4; ++reg) {
            const int rr = rl + quad * 4 + reg;
            const float bias = bp[rr] * bscale;
            #pragma unroll
            for (int nt = 0; nt < 2; ++nt) {
                const int n = n0 + nt * 16 + col;
                const float val = acc[mt][nt][reg] + bias;
                if (gbase < 256)
                    vHT[((size_t)(b * CDIM + rr)) * NSEQ + n] = (_Float16)val;
                else if (gbase < 288)
                    qH[((size_t)(b * NSEQ + n)) * QPDIM + rr] = (_Float16)val;
                else
                    kH[((size_t)(b * NSEQ + n)) * QPDIM + rr] = (_Float16)val;
            }
        }
    }
}

// ---------------------------------------------------------------------------
// K2: mpass partial col-max (log2 domain). grid = 4iq x 4b x 64 jblk = 1024.
// ---------------------------------------------------------------------------
__global__ __launch_bounds__(256, 4) void mpass_kernel(
    const _Float16* __restrict__ qH, const _Float16* __restrict__ kH,
    float* __restrict__ ms4)
{
    __shared__ float wmax[4][32];

    const int blk  = blockIdx.x;
    const int slot = blk & 7;
    const int b    = slot >> 1;
    const int idx  = ((blk >> 3) << 1) | (slot & 1);
    const int jblk = idx & 63;
    const int iq   = idx >> 6;
    const int t    = threadIdx.x;
    const int w    = t >> 6;
    const int lane = t & 63;
    const int l5   = lane >> 5;
    const int lj   = lane & 31;
    const int jt   = w & 1, ih = w >> 1;

    const _Float16* qg = qH + (size_t)b * NSEQ * QPDIM;
    const int j = jblk * 64 + jt * 32 + lj;
    const half8_t kb0 = *(const half8_t*)(
        kH + ((size_t)(b * NSEQ + j)) * QPDIM + l5 * 8);
    const half8_t kb1 = *(const half8_t*)(
        kH + ((size_t)(b * NSEQ + j)) * QPDIM + 16 + l5 * 8);

    float mx = -1e30f;
    const int ibase = iq * 1024 + ih * 512;
    for (int cc = 0; cc < 16; ++cc) {
        const _Float16* qp = qg + (size_t)(ibase + cc * 32 + lj) * QPDIM + l5 * 8;
        half8_t qa0 = *(const half8_t*)qp;
        half8_t qa1 = *(const half8_t*)(qp + 16);
        floatx16 S = __builtin_amdgcn_mfma_f32_32x32x16_f16(
            qa0, kb0, (floatx16){0.f}, 0, 0, 0);
        S = __builtin_amdgcn_mfma_f32_32x32x16_f16(qa1, kb1, S, 0, 0, 0);
        #pragma unroll
        for (int r = 0; r < 16; ++r) mx = fmaxf(mx, S[r]);
    }
    mx = fmaxf(mx, __shfl_xor(mx, 32));
    if (lane < 32) wmax[w][lane] = mx;
    __syncthreads();
    if (t < 64) {
        const int jt3 = t >> 5, c = t & 31;
        ms4[(size_t)iq * (NBATCH * NSEQ) + (size_t)b * NSEQ
            + jblk * 64 + jt3 * 32 + c] = fmaxf(wmax[jt3][c], wmax[jt3 + 2][c]);
    }
}

// ---------------------------------------------------------------------------
// K3: attn. grid = 512 (4b x 64 jblk(64j) x 2 cb(128c)), 256 thr.
// Wave (jh=w&1, ih=w>>1). Pipelined: iter t issues S_t, then PV_{t-1}
// (P held in regs from prev iter), then exp2/transform of S_t overlapping
// PV execution. v triple-buffered (16KB tiles) -> ONE barrier per tile.
// ---------------------------------------------------------------------------
__global__ __launch_bounds__(256, 2) void attn_kernel(
    const _Float16* __restrict__ qH, const _Float16* __restrict__ kH,
    const _Float16* __restrict__ vHT, const float* __restrict__ ms4,
    const float* __restrict__ x, const float* __restrict__ gamma,
    float* __restrict__ out)
{
    __shared__ _Float16 vbuf[3][8192];   // 3 x 16KB v tiles (64i x 128c)
    __shared__ float lred2[2][2][32];    // [jh][ih][j]

    const int blk  = blockIdx.x;
    const int slot = blk & 7;
    const int b    = slot >> 1;
    const int idx  = ((blk >> 3) << 1) | (slot & 1);  // 0..127
    const int cb   = idx >> 6;                        // 0..1
    const int jblk = idx & 63;                        // 0..63
    const int j0   = jblk << 6;
    const int c0   = cb << 7;
    const int t    = threadIdx.x;
    const int w    = t >> 6;
    const int lane = t & 63;
    const int l5   = lane >> 5;
    const int lj   = lane & 31;
    const int jh   = w & 1;
    const int ih   = w >> 1;

    const _Float16* qg = qH + (size_t)b * NSEQ * QPDIM;
    const _Float16* vg = vHT + (size_t)b * CDIM * NSEQ;

    // persistent S B-frags (k of this wave's 32-j tile)
    const int jme = j0 + jh * 32 + lj;
    const half8_t kb0 = *(const half8_t*)(
        kH + ((size_t)(b * NSEQ + jme)) * QPDIM + l5 * 8);
    const half8_t kb1 = *(const half8_t*)(
        kH + ((size_t)(b * NSEQ + jme)) * QPDIM + 16 + l5 * 8);
    const float* msb = ms4 + (size_t)b * NSEQ + jme;
    const float mfix = fmaxf(
        fmaxf(msb[0], msb[NBATCH * NSEQ]),
        fmaxf(msb[2 * NBATCH * NSEQ], msb[3 * NBATCH * NSEQ]));

    // S accumulator init = -mfix (per-lane = per-column j), built ONCE.
    floatx16 cinit;
    #pragma unroll
    for (int r = 0; r < 16; ++r) cinit[r] = -mfix;

    floatx16 acc[4];
    #pragma unroll
    for (int ct = 0; ct < 4; ++ct) acc[ct] = (floatx16){0.f};
    float lp = 0.0f;

    // v DMA: wave w covers units [w*256, +256) = c_local [w*32, +32)
    #define DMA_V(i0_, buf_)                                                   \
        {                                                                      \
            _Pragma("unroll")                                                  \
            for (int g = 0; g < 4; ++g) {                                      \
                const int uu = w * 256 + g * 64 + lane;                        \
                const int cl = uu >> 3;                                        \
                const int ck = (uu & 7) ^ (cl & 7);                            \
                const _Float16* src =                                          \
                    vg + (size_t)(c0 + cl) * NSEQ + (i0_) + ck * 8;            \
                __builtin_amdgcn_global_load_lds(                              \
                    (const __attribute__((address_space(1))) void*)src,        \
                    (__attribute__((address_space(3))) void*)                  \
                        (&vbuf[buf_][(w * 256 + g * 64) * 8]),                 \
                    16, 0, 0);                                                 \
            }                                                                  \
        }

    DMA_V(0, 0);
    const _Float16* qb = qg + (size_t)(ih * 32 + lj) * QPDIM + l5 * 8;
    half8_t qa0 = *(const half8_t*)(qb);
    half8_t qa1 = *(const half8_t*)(qb + 16);

    H8 P0p, P1p;            // P frags of PREVIOUS tile (consumed this iter)
    int bread = 0, bdma = 1, bpv = 2;   // rotating buffer ids

    for (int i0 = 0; i0 < NSEQ; i0 += 64) {
        __syncthreads();   // vbuf[bread] DMA'd; PV_{t-2} reads of bdma done

        if (i0 + 64 < NSEQ) DMA_V(i0 + 64, bdma);

        // ---- S_t (pre-shifted by -mfix via C init) ----
        floatx16 S = __builtin_amdgcn_mfma_f32_32x32x16_f16(
            qa0, kb0, cinit, 0, 0, 0);
        S = __builtin_amdgcn_mfma_f32_32x32x16_f16(qa1, kb1, S, 0, 0, 0);

        // ---- PV_{t-1}: independent of S_t, fills the MFMA pipe while
        //      the VALU below processes exp/transform of S_t ----
        if (i0 != 0) {
            #pragma unroll
            for (int ct = 0; ct < 4; ++ct) {
                const int cl = ct * 32 + lj;
                const int ic0 = (ih * 4 + 0 + l5) ^ (cl & 7);
                const int ic1 = (ih * 4 + 2 + l5) ^ (cl & 7);
                half8_t va0 = *(const half8_t*)&vbuf[bpv][(cl * 8 + ic0) * 8];
                half8_t va1 = *(const half8_t*)&vbuf[bpv][(cl * 8 + ic1) * 8];
                acc[ct] = __builtin_amdgcn_mfma_f32_32x32x16_f16(
                    va0, P0p.h8, acc[ct], 0, 0, 0);
                acc[ct] = __builtin_amdgcn_mfma_f32_32x32x16_f16(
                    va1, P1p.h8, acc[ct], 0, 0, 0);
            }
        }

        // ---- exp2 + pack ----
        H8 lo, hi;
        float ls = 0.0f;
        #pragma unroll
        for (int p = 0; p < 4; ++p) {
            float pa = __builtin_amdgcn_exp2f(S[2 * p]);
            float pb = __builtin_amdgcn_exp2f(S[2 * p + 1]);
            ls += pa + pb;
            lo.h2[p] = pack_f16(pa, pb);
        }
        #pragma unroll
        for (int p = 0; p < 4; ++p) {
            float pa = __builtin_amdgcn_exp2f(S[8 + 2 * p]);
            float pb = __builtin_amdgcn_exp2f(S[8 + 2 * p + 1]);
            ls += pa + pb;
            hi.h2[p] = pack_f16(pa, pb);
        }
        lp += ls;

        // ---- D -> B-operand transform (verified R4/R7) ----
        H8 shl, shh;
        #pragma unroll
        for (int r = 0; r < 4; ++r) {
            shl.i32[r] = __shfl_xor(lo.i32[r], 32);
            shh.i32[r] = __shfl_xor(hi.i32[r], 32);
        }
        const bool high = (l5 != 0);
        P0p.i32[0] = high ? shl.i32[2] : lo.i32[0];
        P0p.i32[1] = high ? shl.i32[3] : lo.i32[1];
        P0p.i32[2] = high ? lo.i32[2]  : shl.i32[0];
        P0p.i32[3] = high ? lo.i32[3]  : shl.i32[1];
        P1p.i32[0] = high ? shh.i32[2] : hi.i32[0];
        P1p.i32[1] = high ? shh.i32[3] : hi.i32[1];
        P1p.i32[2] = high ? hi.i32[2]  : shh.i32[0];
        P1p.i32[3] = high ? hi.i32[3]  : shh.i32[1];

        // prefetch next q frags
        if (i0 + 64 < NSEQ) {
            qa0 = *(const half8_t*)(qb + (size_t)(i0 + 64) * QPDIM);
            qa1 = *(const half8_t*)(qb + (size_t)(i0 + 64) * QPDIM + 16);
        }

        int tmp = bread; bread = bdma; bdma = bpv; bpv = tmp;
    }

    // ---- tail PV (tile 63, buf = bpv after rotation) ----
    #pragma unroll
    for (int ct = 0; ct < 4; ++ct) {
        const int cl = ct * 32 + lj;
        const int ic0 = (ih * 4 + 0 + l5) ^ (cl & 7);
        const int ic1 = (ih * 4 + 2 + l5) ^ (cl & 7);
        half8_t va0 = *(const half8_t*)&vbuf[bpv][(cl * 8 + ic0) * 8];
        half8_t va1 = *(const half8_t*)&vbuf[bpv][(cl * 8 + ic1) * 8];
        acc[ct] = __builtin_amdgcn_mfma_f32_32x32x16_f16(
            va0, P0p.h8, acc[ct], 0, 0, 0);
        acc[ct] = __builtin_amdgcn_mfma_f32_32x32x16_f16(
            va1, P1p.h8, acc[ct], 0, 0, 0);
    }

    // ---- reductions: l across (l5, ih); acc across ih via LDS ----
    lp += __shfl_xor(lp, 32);
    if (lane < 32) lred2[jh][ih][lane] = lp;
    __syncthreads();   // all PV reads of vbuf done before fred reuse

    float* fred = (float*)vbuf;   // 8192 floats = 32 KB, reuse vbuf
    if (ih == 1) {
        #pragma unroll
        for (int ct = 0; ct < 4; ++ct)
            #pragma unroll
            for (int reg = 0; reg < 16; ++reg) {
                const int crow = (reg & 3) + 8 * (reg >> 2) + 4 * l5;
                fred[(ct * 32 + crow) * 64 + jh * 32 + lj] = acc[ct][reg];
            }
    }
    __syncthreads();

    if (ih == 0) {
        const float rv = gamma[0] / (lred2[jh][0][lj] + lred2[jh][1][lj]);
        #pragma unroll
        for (int ct = 0; ct < 4; ++ct) {
            #pragma unroll
            for (int reg = 0; reg < 16; ++reg) {
                const int crow = (reg & 3) + 8 * (reg >> 2) + 4 * l5;
                const int c_ = c0 + ct * 32 + crow;
                const size_t off = ((size_t)(b * CDIM + c_)) * NSEQ + jme;
                const float sum =
                    acc[ct][reg] + fred[(ct * 32 + crow) * 64 + jh * 32 + lj];
                out[off] = sum * rv + x[off];
            }
        }
    }
}

extern "C" void kernel_launch(void* const* d_in, const int* in_sizes, int n_in,
                              void* d_out, int out_size, void* d_ws, size_t ws_size,
                              hipStream_t stream) {
    const float* x     = (const float*)d_in[0];
    const float* Wq    = (const float*)d_in[1];
    const float* bq    = (const float*)d_in[2];
    const float* Wk    = (const float*)d_in[3];
    const float* bk    = (const float*)d_in[4];
    const float* Wv    = (const float*)d_in[5];
    const float* bv    = (const float*)d_in[6];
    const float* gamma = (const float*)d_in[7];
    float* out = (float*)d_out;

    _Float16* w16 = (_Float16*)d_ws;
    _Float16* qH  = w16;                                        // 1 MB
    _Float16* kH  = qH + (size_t)NBATCH * NSEQ * QPDIM;         // 1 MB
    _Float16* vHT = kH + (size_t)NBATCH * NSEQ * QPDIM;         // 8 MB
    _Float16* wH  = vHT + (size_t)NBATCH * CDIM * NSEQ;         // 160 KB
    float*    ms4 = (float*)(wH + (size_t)320 * 256);           // 256 KB

    wprep_kernel<<<40, 256, 0, stream>>>(Wv, Wq, Wk, wH);
    qkv_kernel<<<512, 256, 0, stream>>>(x, wH, bq, bk, bv, qH, kH, vHT);
    mpass_kernel<<<1024, 256, 0, stream>>>(qH, kH, ms4);
    attn_kernel<<<512, 256, 0, stream>>>(qH, kH, vHT, ms4, x, gamma, out);
}